// Round 8
// baseline (334.478 us; speedup 1.0000x reference)
//
#include <hip/hip_runtime.h>

#define BATCH 8
#define GDIM 32
#define NCELL (GDIM * GDIM * GDIM)   // 32768
#define NG (2 * BATCH)               // 16 grids
#define CHN 16                       // scan chunks per grid
#define CCELL (NCELL / CHN)          // 2048 cells per chunk
#define NCHUNK (NG * CHN)            // 256 chunks

// ---------------- helpers ----------------
__device__ __forceinline__ void gridParams(const float* bb, float lo[3],
                                           float inv[3], float cs[3]) {
#pragma unroll
    for (int d = 0; d < 3; ++d) {
        lo[d] = bb[d];
        float span = bb[3 + d] - bb[d];
        float iv = (float)GDIM / (span * (1.f + 1e-6f) + 1e-12f);
        inv[d] = iv;
        cs[d] = 1.f / iv;
    }
}

__device__ __forceinline__ int cellOf(float v, float lo, float inv) {
    return min(max((int)floorf((v - lo) * inv), 0), GDIM - 1);
}

__device__ __forceinline__ float axd(float v, float c0, float cw) {
    return fmaxf(fmaxf(c0 - v, v - (c0 + cw)), 0.f);
}

__device__ __forceinline__ void get4pts(const float4& f0, const float4& f1,
                                        const float4& f2, float px[4],
                                        float py[4], float pz[4]) {
    px[0] = f0.x; py[0] = f0.y; pz[0] = f0.z;
    px[1] = f0.w; py[1] = f1.x; pz[1] = f1.y;
    px[2] = f1.z; py[2] = f1.w; pz[2] = f2.x;
    px[3] = f2.y; py[3] = f2.z; pz[3] = f2.w;
}

// ---------------- k1: bbox (blocks 0..NG-1) + zero cnt (rest) + zero wcount ----------------
__global__ __launch_bounds__(256) void k1_bbox_zero(
    const float* __restrict__ ytrue, const float* __restrict__ ypred,
    int N, float* __restrict__ bbox, uint4* __restrict__ cntz,
    unsigned* __restrict__ wcount)
{
    if (blockIdx.x == 0 && threadIdx.x == 0) *wcount = 0u;
    if (blockIdx.x >= NG) {
        cntz[(blockIdx.x - NG) * 256 + threadIdx.x] = make_uint4(0, 0, 0, 0);
        return;
    }
    int g = blockIdx.x;
    int cloud = g >> 3, b = g & 7;
    const float4* src4 = (const float4*)((cloud ? ypred : ytrue) + (size_t)b * N * 3);
    int nquad = N >> 2;
    float mn[3] = {1e30f, 1e30f, 1e30f}, mx[3] = {-1e30f, -1e30f, -1e30f};
    for (int qk = threadIdx.x; qk < nquad; qk += 256) {
        float4 f0 = src4[3 * qk], f1 = src4[3 * qk + 1], f2 = src4[3 * qk + 2];
        float px[4], py[4], pz[4];
        get4pts(f0, f1, f2, px, py, pz);
#pragma unroll
        for (int k = 0; k < 4; ++k) {
            mn[0] = fminf(mn[0], px[k]); mx[0] = fmaxf(mx[0], px[k]);
            mn[1] = fminf(mn[1], py[k]); mx[1] = fmaxf(mx[1], py[k]);
            mn[2] = fminf(mn[2], pz[k]); mx[2] = fmaxf(mx[2], pz[k]);
        }
    }
#pragma unroll
    for (int o = 32; o; o >>= 1) {
#pragma unroll
        for (int d = 0; d < 3; ++d) {
            mn[d] = fminf(mn[d], __shfl_down(mn[d], o, 64));
            mx[d] = fmaxf(mx[d], __shfl_down(mx[d], o, 64));
        }
    }
    __shared__ float sm[6][4];
    int w = threadIdx.x >> 6, l = threadIdx.x & 63;
    if (l == 0) {
#pragma unroll
        for (int d = 0; d < 3; ++d) { sm[d][w] = mn[d]; sm[3 + d][w] = mx[d]; }
    }
    __syncthreads();
    if (threadIdx.x == 0) {
#pragma unroll
        for (int k = 0; k < 6; ++k) {
            float v = sm[k][0];
#pragma unroll
            for (int i = 1; i < 4; ++i)
                v = (k < 3) ? fminf(v, sm[k][i]) : fmaxf(v, sm[k][i]);
            bbox[g * 6 + k] = v;
        }
    }
}

// ---------------- k2: histogram ----------------
__global__ __launch_bounds__(256) void k2_hist(
    const float* __restrict__ ytrue, const float* __restrict__ ypred,
    int N, const float* __restrict__ bbox, unsigned* __restrict__ cnt)
{
    int nquad = N >> 2;
    int bpg = nquad >> 8;
    int g = blockIdx.x / bpg;
    int qk = (blockIdx.x - g * bpg) * 256 + threadIdx.x;
    int cloud = g >> 3, b = g & 7;
    const float4* src4 = (const float4*)((cloud ? ypred : ytrue) + (size_t)b * N * 3);
    float lo[3], inv[3], cs[3];
    gridParams(bbox + g * 6, lo, inv, cs);
    float4 f0 = src4[3 * qk], f1 = src4[3 * qk + 1], f2 = src4[3 * qk + 2];
    float px[4], py[4], pz[4];
    get4pts(f0, f1, f2, px, py, pz);
    unsigned* Cg = cnt + (size_t)g * NCELL;
#pragma unroll
    for (int k = 0; k < 4; ++k) {
        int cx = cellOf(px[k], lo[0], inv[0]);
        int cy = cellOf(py[k], lo[1], inv[1]);
        int cz = cellOf(pz[k], lo[2], inv[2]);
        atomicAdd(&Cg[(cz * GDIM + cy) * GDIM + cx], 1u);
    }
}

// ---------------- k3a: per-chunk local scan, pack (localrun<<16)|cnt, zero fill ----------------
__global__ __launch_bounds__(256) void k3a(
    unsigned* __restrict__ cnt, unsigned* __restrict__ sc,
    unsigned* __restrict__ bsum)
{
    int chunk = blockIdx.x;              // 0..255
    unsigned* c = cnt + (size_t)chunk * CCELL;
    unsigned* out = sc + (size_t)chunk * CCELL;
    int t = threadIdx.x;
    uint4 v0, v1;
    const uint4* c4 = (const uint4*)(c + t * 8);
    v0 = c4[0]; v1 = c4[1];
    unsigned s = v0.x + v0.y + v0.z + v0.w + v1.x + v1.y + v1.z + v1.w;
    __shared__ unsigned sd[256];
    sd[t] = s;
    __syncthreads();
    unsigned val = s;
    for (int off = 1; off < 256; off <<= 1) {
        unsigned o = (t >= off) ? sd[t - off] : 0u;
        __syncthreads();
        val += o;
        sd[t] = val;
        __syncthreads();
    }
    unsigned run = val - s;
    uint4* o4 = (uint4*)(out + t * 8);
    uint4* z4 = (uint4*)(c + t * 8);
    uint4 w0, w1;
    w0.x = (run << 16) | v0.x; run += v0.x;
    w0.y = (run << 16) | v0.y; run += v0.y;
    w0.z = (run << 16) | v0.z; run += v0.z;
    w0.w = (run << 16) | v0.w; run += v0.w;
    w1.x = (run << 16) | v1.x; run += v1.x;
    w1.y = (run << 16) | v1.y; run += v1.y;
    w1.z = (run << 16) | v1.z; run += v1.z;
    w1.w = (run << 16) | v1.w; run += v1.w;
    o4[0] = w0; o4[1] = w1;
    z4[0] = make_uint4(0, 0, 0, 0);
    z4[1] = make_uint4(0, 0, 0, 0);
    if (t == 255) bsum[chunk] = val;     // inclusive total of this chunk
}

// ---------------- k3b: per-grid segmented exclusive scan of chunk sums ----------------
__global__ __launch_bounds__(256) void k3b(
    const unsigned* __restrict__ bsum, unsigned* __restrict__ coff)
{
    __shared__ unsigned sb[NCHUNK];
    int t = threadIdx.x;
    sb[t] = bsum[t];
    __syncthreads();
    int grid = t >> 4, idx = t & 15;
    unsigned off = 0;
    for (int i = 0; i < idx; ++i) off += sb[(grid << 4) + i];
    coff[t] = off;
}

// ---------------- k3c: add chunk offsets to start fields ----------------
__global__ __launch_bounds__(256) void k3c(
    unsigned* __restrict__ sc, const unsigned* __restrict__ coff)
{
    int chunk = blockIdx.x;
    unsigned add = coff[chunk] << 16;
    if (add == 0u) return;
    uint4* o4 = (uint4*)(sc + (size_t)chunk * CCELL) + threadIdx.x * 2;
    uint4 a = o4[0], b = o4[1];
    a.x += add; a.y += add; a.z += add; a.w += add;
    b.x += add; b.y += add; b.z += add; b.w += add;
    o4[0] = a; o4[1] = b;
}

// ---------------- k4: scatter ----------------
__global__ __launch_bounds__(256) void k4_scatter(
    const float* __restrict__ ytrue, const float* __restrict__ ypred,
    int N, const float* __restrict__ bbox, const unsigned* __restrict__ sc,
    unsigned* __restrict__ fill, float4* __restrict__ sorted)
{
    int nquad = N >> 2;
    int bpg = nquad >> 8;
    int g = blockIdx.x / bpg;
    int qk = (blockIdx.x - g * bpg) * 256 + threadIdx.x;
    int cloud = g >> 3, b = g & 7;
    const float4* src4 = (const float4*)((cloud ? ypred : ytrue) + (size_t)b * N * 3);
    float lo[3], inv[3], cs[3];
    gridParams(bbox + g * 6, lo, inv, cs);
    float4 f0 = src4[3 * qk], f1 = src4[3 * qk + 1], f2 = src4[3 * qk + 2];
    float px[4], py[4], pz[4];
    get4pts(f0, f1, f2, px, py, pz);
    const unsigned* Sg = sc + (size_t)g * NCELL;
    unsigned* Fg = fill + (size_t)g * NCELL;
    float4* Og = sorted + (size_t)g * N;
#pragma unroll
    for (int k = 0; k < 4; ++k) {
        int cx = cellOf(px[k], lo[0], inv[0]);
        int cy = cellOf(py[k], lo[1], inv[1]);
        int cz = cellOf(pz[k], lo[2], inv[2]);
        int cid = (cz * GDIM + cy) * GDIM + cx;
        unsigned pos = (Sg[cid] >> 16) + atomicAdd(&Fg[cid], 1u);
        Og[pos] = make_float4(px[k], py[k], pz[k],
                              fmaf(px[k], px[k], fmaf(py[k], py[k], pz[k] * pz[k])));
    }
}

// ---------------- k5a: 32 queries/wave (2 lanes each), union-box uniform stream ----------------
__global__ __launch_bounds__(256) void k5a(
    const float4* __restrict__ sorted, const unsigned* __restrict__ sc,
    const float* __restrict__ bbox, int N, double* __restrict__ partialA,
    uint2* __restrict__ wlist, unsigned* __restrict__ wcount)
{
    const int lane = threadIdx.x & 63, wid = threadIdx.x >> 6;
    const int qs = lane & 31;              // query slot
    const unsigned half = (unsigned)(lane >> 5);
    int w = (int)blockIdx.x * 4 + wid;     // wave id, 0..4095
    int qglob = w * 32 + qs;
    int g = qglob / N;                     // uniform (32 | N)
    int qi = qglob - g * N;
    int cloud = g >> 3, b = g & 7;
    int gr = ((1 - cloud) << 3) | b;

    float lo[3], inv[3], cs[3];
    gridParams(bbox + gr * 6, lo, inv, cs);
    const unsigned* __restrict__ C = sc + (size_t)gr * NCELL;
    const float4* __restrict__ P = sorted + (size_t)gr * N;

    float4 q = sorted[(size_t)g * N + qi];
    float q2 = q.w;
    float nqx = -2.f * q.x, nqy = -2.f * q.y, nqz = -2.f * q.z;
    float tb = 1e30f;

    int cx = cellOf(q.x, lo[0], inv[0]);
    int cy = cellOf(q.y, lo[1], inv[1]);
    int cz = cellOf(q.z, lo[2], inv[2]);
    int mnx = cx, mxx = cx, mny = cy, mxy = cy, mnz = cz, mxz = cz;
#pragma unroll
    for (int o = 32; o; o >>= 1) {
        mnx = min(mnx, __shfl_xor(mnx, o, 64)); mxx = max(mxx, __shfl_xor(mxx, o, 64));
        mny = min(mny, __shfl_xor(mny, o, 64)); mxy = max(mxy, __shfl_xor(mxy, o, 64));
        mnz = min(mnz, __shfl_xor(mnz, o, 64)); mxz = max(mxz, __shfl_xor(mxz, o, 64));
    }
    int x0 = __builtin_amdgcn_readfirstlane(max(mnx - 1, 0));
    int x1 = __builtin_amdgcn_readfirstlane(min(mxx + 1, GDIM - 1));
    int y0 = __builtin_amdgcn_readfirstlane(max(mny - 1, 0));
    int y1 = __builtin_amdgcn_readfirstlane(min(mxy + 1, GDIM - 1));
    int z0 = __builtin_amdgcn_readfirstlane(max(mnz - 1, 0));
    int z1 = __builtin_amdgcn_readfirstlane(min(mxz + 1, GDIM - 1));

    int ny = y1 - y0 + 1;
    int nrows = (z1 - z0 + 1) * ny;

    for (int rb = 0; rb < nrows; rb += 64) {
        int rr = min(rb + lane, nrows - 1);
        int zi = z0 + rr / ny;
        int yi = y0 + rr - (rr / ny) * ny;
        const unsigned* rowp = C + (zi * GDIM + yi) * GDIM;
        unsigned hA = rowp[x0];
        unsigned hB = rowp[x1];
        int rend = min(64, nrows - rb);
        for (int ri = 0; ri < rend; ++ri) {
            unsigned ha = (unsigned)__builtin_amdgcn_readlane((int)hA, ri);
            unsigned hb = (unsigned)__builtin_amdgcn_readlane((int)hB, ri);
            unsigned rs = ha >> 16;
            unsigned re = (hb >> 16) + (hb & 0xffffu);
#pragma unroll 4
            for (unsigned j = rs + half; j < re; j += 2) {
                float4 p = P[j];   // 2 distinct addresses/wave -> near-broadcast
                float t = fmaf(nqx, p.x, fmaf(nqy, p.y, fmaf(nqz, p.z, p.w)));
                tb = fminf(tb, t);
            }
        }
    }

    tb = fminf(tb, __shfl_xor(tb, 32, 64));   // merge odd/even halves
    float d2 = q2 + tb;

    // termination vs union-box faces (exact: whole box was scanned)
    float mx = fminf(x0 > 0 ? q.x - (lo[0] + x0 * cs[0]) : 1e30f,
                     x1 < GDIM - 1 ? (lo[0] + (x1 + 1) * cs[0]) - q.x : 1e30f);
    float my = fminf(y0 > 0 ? q.y - (lo[1] + y0 * cs[1]) : 1e30f,
                     y1 < GDIM - 1 ? (lo[1] + (y1 + 1) * cs[1]) - q.y : 1e30f);
    float mz = fminf(z0 > 0 ? q.z - (lo[2] + z0 * cs[2]) : 1e30f,
                     z1 < GDIM - 1 ? (lo[2] + (z1 + 1) * cs[2]) - q.z : 1e30f);
    float m = fminf(mx, fminf(my, mz));
    bool done = (m > 0.f) && (m * m * 0.999f >= d2);
    bool isq = (half == 0u);

    unsigned long long fmask = __ballot((int)(isq && !done));
    double acc = (isq && done) ? (double)fmaxf(0.f, d2) : 0.0;
    if (fmask) {
        int nf = __popcll(fmask);
        unsigned base = 0;
        if (lane == 0) base = atomicAdd(wcount, (unsigned)nf);
        base = (unsigned)__shfl((int)base, 0, 64);
        if (isq && !done) {
            int pos = __popcll(fmask & ((1ull << lane) - 1ull));
            wlist[base + pos] = make_uint2((unsigned)qglob, __float_as_uint(tb));
        }
    }

#pragma unroll
    for (int o = 32; o; o >>= 1) acc += __shfl_down(acc, o, 64);
    __shared__ double sd[4];
    if (lane == 0) sd[wid] = acc;
    __syncthreads();
    if (threadIdx.x == 0)
        partialA[blockIdx.x] = sd[0] + sd[1] + sd[2] + sd[3];
}

// ---------------- k5b: worklist, shells r=2..4 then coalesced brute fallback ----------------
__global__ __launch_bounds__(256) void k5b(
    const float4* __restrict__ sorted, const unsigned* __restrict__ sc,
    const float* __restrict__ bbox, int N, const uint2* __restrict__ wlist,
    const unsigned* __restrict__ wcount, double* __restrict__ partialB)
{
    const int lane = threadIdx.x & 63;
    const int wid = threadIdx.x >> 6;
    int W = (int)blockIdx.x * 4 + wid;
    int nW = (int)gridDim.x * 4;
    unsigned count = *wcount;
    double acc = 0.0;

    for (unsigned wi = (unsigned)W; wi < count; wi += (unsigned)nW) {
        uint2 e = wlist[wi];
        int qglob = (int)e.x;
        float tb = __uint_as_float(e.y);
        int g = qglob / N;
        int qi = qglob - g * N;
        int cloud = g >> 3, b = g & 7;
        int gr = ((1 - cloud) << 3) | b;

        float lo[3], inv[3], cs[3];
        gridParams(bbox + gr * 6, lo, inv, cs);
        const unsigned* __restrict__ C = sc + (size_t)gr * NCELL;
        const float4* __restrict__ P = sorted + (size_t)gr * N;

        float4 q = sorted[(size_t)g * N + qi];
        float q2 = q.w;
        float nqx = -2.f * q.x, nqy = -2.f * q.y, nqz = -2.f * q.z;
        int cx = cellOf(q.x, lo[0], inv[0]);
        int cy = cellOf(q.y, lo[1], inv[1]);
        int cz = cellOf(q.z, lo[2], inv[2]);
        float d2cur = q2 + tb;
        bool finished = false;

        for (int r = 2; r <= 4; ++r) {
            int L = 2 * r + 1;
            int S = L * L;
            int ring = 8 * r;
            int scnt = 2 * S + (2 * r - 1) * ring;
            for (int s0 = 0; s0 < scnt; s0 += 64) {
                int si = s0 + lane;
                unsigned cn = 0, st = 0;
                if (si < scnt) {
                    int dx, dy, dz;
                    if (si < S) {
                        dz = -r; dx = si % L - r; dy = si / L - r;
                    } else if (si < 2 * S) {
                        int t = si - S;
                        dz = r; dx = t % L - r; dy = t / L - r;
                    } else {
                        int rem = si - 2 * S;
                        int lvl = rem / ring;
                        dz = -r + 1 + lvl;
                        int pos = rem - lvl * ring;
                        int side = pos / (2 * r);
                        int o = pos - side * 2 * r;
                        if (side == 0)      { dy = -r; dx = -r + o; }
                        else if (side == 1) { dx = r;  dy = -r + o; }
                        else if (side == 2) { dy = r;  dx = r - o; }
                        else                { dx = -r; dy = r - o; }
                    }
                    int xx = cx + dx, yy = cy + dy, zz = cz + dz;
                    if (xx >= 0 && xx < GDIM && yy >= 0 && yy < GDIM &&
                        zz >= 0 && zz < GDIM) {
                        float ddx = axd(q.x, lo[0] + xx * cs[0], cs[0]);
                        float ddy = axd(q.y, lo[1] + yy * cs[1], cs[1]);
                        float ddz = axd(q.z, lo[2] + zz * cs[2], cs[2]);
                        float lb2 = fmaf(ddx, ddx, fmaf(ddy, ddy, ddz * ddz));
                        if (lb2 * 0.999f < d2cur) {
                            unsigned h = C[(zz * GDIM + yy) * GDIM + xx];
                            st = h >> 16;
                            cn = h & 0xffffu;
                        }
                    }
                }
                unsigned mc = cn;
#pragma unroll
                for (int o = 1; o < 64; o <<= 1)
                    mc = max(mc, (unsigned)__shfl_xor((int)mc, o, 64));
#pragma unroll 4
                for (unsigned j = 0; j < mc; ++j) {
                    if (j < cn) {
                        float4 p = P[st + j];
                        float t = fmaf(nqx, p.x, fmaf(nqy, p.y, fmaf(nqz, p.z, p.w)));
                        tb = fminf(tb, t);
                    }
                }
            }
#pragma unroll
            for (int o = 1; o < 64; o <<= 1)
                tb = fminf(tb, __shfl_xor(tb, o, 64));
            d2cur = q2 + tb;

            int x0 = max(cx - r, 0), x1 = min(cx + r, GDIM - 1);
            int y0 = max(cy - r, 0), y1 = min(cy + r, GDIM - 1);
            int z0 = max(cz - r, 0), z1 = min(cz + r, GDIM - 1);
            bool full = (x0 == 0 && y0 == 0 && z0 == 0 &&
                         x1 == GDIM - 1 && y1 == GDIM - 1 && z1 == GDIM - 1);
            float mx = fminf(x0 > 0 ? q.x - (lo[0] + x0 * cs[0]) : 1e30f,
                             x1 < GDIM - 1 ? (lo[0] + (x1 + 1) * cs[0]) - q.x : 1e30f);
            float my = fminf(y0 > 0 ? q.y - (lo[1] + y0 * cs[1]) : 1e30f,
                             y1 < GDIM - 1 ? (lo[1] + (y1 + 1) * cs[1]) - q.y : 1e30f);
            float mz = fminf(z0 > 0 ? q.z - (lo[2] + z0 * cs[2]) : 1e30f,
                             z1 < GDIM - 1 ? (lo[2] + (z1 + 1) * cs[2]) - q.z : 1e30f);
            float m = fminf(mx, fminf(my, mz));
            bool done = (m > 0.f) && (m * m * 0.999f >= d2cur);
            if (full || done) { finished = true; break; }
        }

        if (!finished) {   // coalesced brute scan of all refs (exact, bounded)
#pragma unroll 4
            for (int j = lane; j < N; j += 64) {
                float4 p = P[j];
                float t = fmaf(nqx, p.x, fmaf(nqy, p.y, fmaf(nqz, p.z, p.w)));
                tb = fminf(tb, t);
            }
#pragma unroll
            for (int o = 1; o < 64; o <<= 1)
                tb = fminf(tb, __shfl_xor(tb, o, 64));
            d2cur = q2 + tb;
        }
        acc += (double)fmaxf(0.f, d2cur);
    }

    __shared__ double sd[4];
    if (lane == 0) sd[wid] = acc;
    __syncthreads();
    if (threadIdx.x == 0)
        partialB[blockIdx.x] = sd[0] + sd[1] + sd[2] + sd[3];
}

// ---------------- k6: final reduction ----------------
__global__ __launch_bounds__(256) void k6_final(
    const double* __restrict__ pA, int nA, const double* __restrict__ pB,
    int nB, float* __restrict__ out)
{
    double s = 0.0;
    for (int i = threadIdx.x; i < nA; i += 256) s += pA[i];
    for (int i = threadIdx.x; i < nB; i += 256) s += pB[i];
#pragma unroll
    for (int o = 32; o; o >>= 1) s += __shfl_down(s, o, 64);
    __shared__ double sd[4];
    int wid = threadIdx.x >> 6, lane = threadIdx.x & 63;
    if (lane == 0) sd[wid] = s;
    __syncthreads();
    if (threadIdx.x == 0)
        out[0] = (float)((sd[0] + sd[1] + sd[2] + sd[3]) / (double)BATCH);
}

extern "C" void kernel_launch(void* const* d_in, const int* in_sizes, int n_in,
                              void* d_out, int out_size, void* d_ws, size_t ws_size,
                              hipStream_t stream)
{
    const float* ytrue = (const float*)d_in[0];
    const float* ypred = (const float*)d_in[1];
    int N = in_sizes[0] / (BATCH * 3);          // 8192
    size_t total = (size_t)NG * N;              // 131072
    int nwA = (int)(total / 32);                // 4096 waves
    int blkA = nwA / 4;                         // 1024 blocks
    int blkB = 1024;

    char* ws = (char*)d_ws;
    float4*   sorted  = (float4*)ws;   ws += total * sizeof(float4);     // 2 MB
    unsigned* cnt     = (unsigned*)ws; ws += (size_t)NG * NCELL * 4;     // 2 MB (fill)
    unsigned* sc      = (unsigned*)ws; ws += (size_t)NG * NCELL * 4;     // 2 MB
    uint2*    wlist   = (uint2*)ws;    ws += total * sizeof(uint2);      // 1 MB
    double*   partialA = (double*)ws;  ws += (size_t)blkA * 8;
    double*   partialB = (double*)ws;  ws += (size_t)blkB * 8;
    unsigned* bsum    = (unsigned*)ws; ws += NCHUNK * 4;
    unsigned* coff    = (unsigned*)ws; ws += NCHUNK * 4;
    float*    bbox    = (float*)ws;    ws += NG * 6 * sizeof(float);
    unsigned* wcount  = (unsigned*)ws; ws += 16;

    k1_bbox_zero<<<NG + 512, 256, 0, stream>>>(ytrue, ypred, N, bbox,
                                               (uint4*)cnt, wcount);
    int ptB = (int)(total / 4 / 256);           // 128 blocks
    k2_hist<<<ptB, 256, 0, stream>>>(ytrue, ypred, N, bbox, cnt);
    k3a<<<NCHUNK, 256, 0, stream>>>(cnt, sc, bsum);
    k3b<<<1, 256, 0, stream>>>(bsum, coff);
    k3c<<<NCHUNK, 256, 0, stream>>>(sc, coff);
    k4_scatter<<<ptB, 256, 0, stream>>>(ytrue, ypred, N, bbox, sc, cnt, sorted);
    k5a<<<blkA, 256, 0, stream>>>(sorted, sc, bbox, N, partialA, wlist, wcount);
    k5b<<<blkB, 256, 0, stream>>>(sorted, sc, bbox, N, wlist, wcount, partialB);
    k6_final<<<1, 256, 0, stream>>>(partialA, blkA, partialB, blkB,
                                    (float*)d_out);
}

// Round 9
// 167.453 us; speedup vs baseline: 1.9974x; 1.9974x over previous
//
#include <hip/hip_runtime.h>

#define BATCH 8
#define GDIM 32
#define NCELL (GDIM * GDIM * GDIM)   // 32768
#define NG (2 * BATCH)               // 16 grids
#define K5B_BLK 2048

// ---------------- helpers ----------------
__device__ __forceinline__ void gridParams(const float* bb, float lo[3],
                                           float inv[3], float cs[3]) {
#pragma unroll
    for (int d = 0; d < 3; ++d) {
        lo[d] = bb[d];
        float span = bb[3 + d] - bb[d];
        float iv = (float)GDIM / (span * (1.f + 1e-6f) + 1e-12f);
        inv[d] = iv;
        cs[d] = 1.f / iv;
    }
}

__device__ __forceinline__ int cellOf(float v, float lo, float inv) {
    return min(max((int)floorf((v - lo) * inv), 0), GDIM - 1);
}

__device__ __forceinline__ void get4pts(const float4& f0, const float4& f1,
                                        const float4& f2, float px[4],
                                        float py[4], float pz[4]) {
    px[0] = f0.x; py[0] = f0.y; pz[0] = f0.z;
    px[1] = f0.w; py[1] = f1.x; pz[1] = f1.y;
    px[2] = f1.z; py[2] = f1.w; pz[2] = f2.x;
    px[3] = f2.y; py[3] = f2.z; pz[3] = f2.w;
}

// ---------------- k1: bbox (blocks 0..NG-1) + zero cnt (rest) + zero wcnt ----------------
__global__ __launch_bounds__(256) void k1_bbox_zero(
    const float* __restrict__ ytrue, const float* __restrict__ ypred,
    int N, float* __restrict__ bbox, uint4* __restrict__ cntz,
    unsigned* __restrict__ wcnt)
{
    if (blockIdx.x == 0 && threadIdx.x < NG) wcnt[threadIdx.x] = 0u;
    if (blockIdx.x >= NG) {
        cntz[(blockIdx.x - NG) * 256 + threadIdx.x] = make_uint4(0, 0, 0, 0);
        return;
    }
    int g = blockIdx.x;
    int cloud = g >> 3, b = g & 7;
    const float4* src4 = (const float4*)((cloud ? ypred : ytrue) + (size_t)b * N * 3);
    int nquad = N >> 2;
    float mn[3] = {1e30f, 1e30f, 1e30f}, mx[3] = {-1e30f, -1e30f, -1e30f};
    for (int qk = threadIdx.x; qk < nquad; qk += 256) {
        float4 f0 = src4[3 * qk], f1 = src4[3 * qk + 1], f2 = src4[3 * qk + 2];
        float px[4], py[4], pz[4];
        get4pts(f0, f1, f2, px, py, pz);
#pragma unroll
        for (int k = 0; k < 4; ++k) {
            mn[0] = fminf(mn[0], px[k]); mx[0] = fmaxf(mx[0], px[k]);
            mn[1] = fminf(mn[1], py[k]); mx[1] = fmaxf(mx[1], py[k]);
            mn[2] = fminf(mn[2], pz[k]); mx[2] = fmaxf(mx[2], pz[k]);
        }
    }
#pragma unroll
    for (int o = 32; o; o >>= 1) {
#pragma unroll
        for (int d = 0; d < 3; ++d) {
            mn[d] = fminf(mn[d], __shfl_down(mn[d], o, 64));
            mx[d] = fmaxf(mx[d], __shfl_down(mx[d], o, 64));
        }
    }
    __shared__ float sm[6][4];
    int w = threadIdx.x >> 6, l = threadIdx.x & 63;
    if (l == 0) {
#pragma unroll
        for (int d = 0; d < 3; ++d) { sm[d][w] = mn[d]; sm[3 + d][w] = mx[d]; }
    }
    __syncthreads();
    if (threadIdx.x == 0) {
#pragma unroll
        for (int k = 0; k < 6; ++k) {
            float v = sm[k][0];
#pragma unroll
            for (int i = 1; i < 4; ++i)
                v = (k < 3) ? fminf(v, sm[k][i]) : fmaxf(v, sm[k][i]);
            bbox[g * 6 + k] = v;
        }
    }
}

// ---------------- k2: histogram ----------------
__global__ __launch_bounds__(256) void k2_hist(
    const float* __restrict__ ytrue, const float* __restrict__ ypred,
    int N, const float* __restrict__ bbox, unsigned* __restrict__ cnt)
{
    int nquad = N >> 2;
    int bpg = nquad >> 8;
    int g = blockIdx.x / bpg;
    int qk = (blockIdx.x - g * bpg) * 256 + threadIdx.x;
    int cloud = g >> 3, b = g & 7;
    const float4* src4 = (const float4*)((cloud ? ypred : ytrue) + (size_t)b * N * 3);
    float lo[3], inv[3], cs[3];
    gridParams(bbox + g * 6, lo, inv, cs);
    float4 f0 = src4[3 * qk], f1 = src4[3 * qk + 1], f2 = src4[3 * qk + 2];
    float px[4], py[4], pz[4];
    get4pts(f0, f1, f2, px, py, pz);
    unsigned* Cg = cnt + (size_t)g * NCELL;
#pragma unroll
    for (int k = 0; k < 4; ++k) {
        int cx = cellOf(px[k], lo[0], inv[0]);
        int cy = cellOf(py[k], lo[1], inv[1]);
        int cz = cellOf(pz[k], lo[2], inv[2]);
        atomicAdd(&Cg[(cz * GDIM + cy) * GDIM + cx], 1u);
    }
}

// ---------------- k3: per-grid scan, pack (start<<16)|cnt, zero fill ----------------
__global__ __launch_bounds__(1024) void k3_scan(
    unsigned* __restrict__ cnt, unsigned* __restrict__ sc)
{
    int g = blockIdx.x;
    unsigned* c = cnt + (size_t)g * NCELL;
    unsigned* out = sc + (size_t)g * NCELL;
    int t = threadIdx.x;
    uint4 v[8];
    const uint4* c4 = (const uint4*)(c + t * 32);
    unsigned sum = 0;
#pragma unroll
    for (int j = 0; j < 8; ++j) {
        v[j] = c4[j];
        sum += v[j].x + v[j].y + v[j].z + v[j].w;
    }
    __shared__ unsigned sd[1024];
    sd[t] = sum;
    __syncthreads();
    unsigned val = sum;
    for (int off = 1; off < 1024; off <<= 1) {
        unsigned o = (t >= off) ? sd[t - off] : 0u;
        __syncthreads();
        val += o;
        sd[t] = val;
        __syncthreads();
    }
    unsigned run = val - sum;
    uint4* o4 = (uint4*)(out + t * 32);
    uint4* z4 = (uint4*)(c + t * 32);
#pragma unroll
    for (int j = 0; j < 8; ++j) {
        uint4 w;
        w.x = (run << 16) | v[j].x; run += v[j].x;
        w.y = (run << 16) | v[j].y; run += v[j].y;
        w.z = (run << 16) | v[j].z; run += v[j].z;
        w.w = (run << 16) | v[j].w; run += v[j].w;
        o4[j] = w;
        z4[j] = make_uint4(0, 0, 0, 0);
    }
}

// ---------------- k4: scatter ----------------
__global__ __launch_bounds__(256) void k4_scatter(
    const float* __restrict__ ytrue, const float* __restrict__ ypred,
    int N, const float* __restrict__ bbox, const unsigned* __restrict__ sc,
    unsigned* __restrict__ fill, float4* __restrict__ sorted)
{
    int nquad = N >> 2;
    int bpg = nquad >> 8;
    int g = blockIdx.x / bpg;
    int qk = (blockIdx.x - g * bpg) * 256 + threadIdx.x;
    int cloud = g >> 3, b = g & 7;
    const float4* src4 = (const float4*)((cloud ? ypred : ytrue) + (size_t)b * N * 3);
    float lo[3], inv[3], cs[3];
    gridParams(bbox + g * 6, lo, inv, cs);
    float4 f0 = src4[3 * qk], f1 = src4[3 * qk + 1], f2 = src4[3 * qk + 2];
    float px[4], py[4], pz[4];
    get4pts(f0, f1, f2, px, py, pz);
    const unsigned* Sg = sc + (size_t)g * NCELL;
    unsigned* Fg = fill + (size_t)g * NCELL;
    float4* Og = sorted + (size_t)g * N;
#pragma unroll
    for (int k = 0; k < 4; ++k) {
        int cx = cellOf(px[k], lo[0], inv[0]);
        int cy = cellOf(py[k], lo[1], inv[1]);
        int cz = cellOf(pz[k], lo[2], inv[2]);
        int cid = (cz * GDIM + cy) * GDIM + cx;
        unsigned pos = (Sg[cid] >> 16) + atomicAdd(&Fg[cid], 1u);
        Og[pos] = make_float4(px[k], py[k], pz[k],
                              fmaf(px[k], px[k], fmaf(py[k], py[k], pz[k] * pz[k])));
    }
}

// ---------------- k5a: one query per 16-lane group; 9 row-segments, flat stream ----------------
__global__ __launch_bounds__(256) void k5a(
    const float4* __restrict__ sorted, const unsigned* __restrict__ sc,
    const float* __restrict__ bbox, int N, double* __restrict__ partialA,
    unsigned* __restrict__ wlist, unsigned* __restrict__ wcnt)
{
    const int lane = threadIdx.x & 63, wid = threadIdx.x >> 6;
    const int s = threadIdx.x & 15;
    int qglob = (int)blockIdx.x * 16 + (threadIdx.x >> 4);
    int g = qglob / N;
    int qi = qglob - g * N;
    int cloud = g >> 3, b = g & 7;
    int gr = ((1 - cloud) << 3) | b;

    float lo[3], inv[3], cs[3];
    gridParams(bbox + gr * 6, lo, inv, cs);
    const unsigned* __restrict__ C = sc + (size_t)gr * NCELL;
    const float4* __restrict__ P = sorted + (size_t)gr * N;

    float4 q = sorted[(size_t)g * N + qi];   // broadcast within group
    float q2 = q.w;
    float nqx = -2.f * q.x, nqy = -2.f * q.y, nqz = -2.f * q.z;
    float tb = 1e30f;

    int cx = cellOf(q.x, lo[0], inv[0]);
    int cy = cellOf(q.y, lo[1], inv[1]);
    int cz = cellOf(q.z, lo[2], inv[2]);
    int x0 = max(cx - 1, 0), x1 = min(cx + 1, GDIM - 1);

    // lane s<9 owns row (dy,dz) = (s%3-1, s/3-1)
    unsigned segstart = 0, len = 0;
    if (s < 9) {
        int yi = cy + (s % 3) - 1;
        int zi = cz + (s / 3) - 1;
        if (yi >= 0 && yi < GDIM && zi >= 0 && zi < GDIM) {
            const unsigned* rowp = C + (zi * GDIM + yi) * GDIM;
            unsigned hA = rowp[x0];
            unsigned hB = rowp[x1];
            segstart = hA >> 16;
            len = (hB >> 16) + (hB & 0xffffu) - segstart;
        }
    }
    // 16-lane prefix scan of len
    unsigned incl = len;
#pragma unroll
    for (int o = 1; o < 16; o <<= 1) {
        unsigned u = __shfl_up(incl, o, 16);
        if (s >= o) incl += u;
    }
    unsigned excl = incl - len;
    unsigned T = (unsigned)__shfl((int)incl, 15, 16);
    // broadcast 9 (pref,start) pairs into registers
    unsigned pk[9], sk[9];
#pragma unroll
    for (int k = 0; k < 9; ++k) {
        pk[k] = (unsigned)__shfl((int)excl, k, 16);
        sk[k] = (unsigned)__shfl((int)segstart, k, 16);
    }

    for (unsigned t = (unsigned)s; t < T; t += 16u) {
        unsigned idx = sk[0] + t;   // pk[0] == 0
#pragma unroll
        for (int k = 1; k < 9; ++k)
            if (t >= pk[k]) idx = sk[k] + (t - pk[k]);
        float4 p = P[idx];
        float tt = fmaf(nqx, p.x, fmaf(nqy, p.y, fmaf(nqz, p.z, p.w)));
        tb = fminf(tb, tt);
    }
#pragma unroll
    for (int o = 1; o < 16; o <<= 1)
        tb = fminf(tb, __shfl_xor(tb, o, 16));
    float d2 = fmaxf(0.f, q2 + tb);

    int y0 = max(cy - 1, 0), y1 = min(cy + 1, GDIM - 1);
    int z0 = max(cz - 1, 0), z1 = min(cz + 1, GDIM - 1);
    float mx = fminf(x0 > 0 ? q.x - (lo[0] + x0 * cs[0]) : 1e30f,
                     x1 < GDIM - 1 ? (lo[0] + (x1 + 1) * cs[0]) - q.x : 1e30f);
    float my = fminf(y0 > 0 ? q.y - (lo[1] + y0 * cs[1]) : 1e30f,
                     y1 < GDIM - 1 ? (lo[1] + (y1 + 1) * cs[1]) - q.y : 1e30f);
    float mz = fminf(z0 > 0 ? q.z - (lo[2] + z0 * cs[2]) : 1e30f,
                     z1 < GDIM - 1 ? (lo[2] + (z1 + 1) * cs[2]) - q.z : 1e30f);
    float m = fminf(mx, fminf(my, mz));
    bool done = (m > 0.f) && (m * m * 0.999f >= d2);

    double val = 0.0;
    if (s == 0) {
        if (done) {
            val = (double)d2;
        } else {
            unsigned i2 = atomicAdd(&wcnt[g], 1u);
            wlist[(size_t)g * N + i2] = (unsigned)qi;
        }
    }
#pragma unroll
    for (int o = 32; o; o >>= 1) val += __shfl_down(val, o, 64);
    __shared__ double sd[4];
    if (lane == 0) sd[wid] = val;
    __syncthreads();
    if (threadIdx.x == 0)
        partialA[blockIdx.x] = sd[0] + sd[1] + sd[2] + sd[3];
}

// ---------------- k5b: worklist brute force; 8 same-grid queries per wave ----------------
__global__ __launch_bounds__(256) void k5b(
    const float4* __restrict__ sorted, const unsigned* __restrict__ wlist,
    const unsigned* __restrict__ wcnt, int N, double* __restrict__ partialB)
{
    const int lane = threadIdx.x & 63, wid = threadIdx.x >> 6;
    int g = (int)blockIdx.x & 15;
    int ci = (int)blockIdx.x >> 4;           // 0..127
    int cloud = g >> 3, b = g & 7;
    int gr = ((1 - cloud) << 3) | b;
    const float4* __restrict__ P = sorted + (size_t)gr * N;
    const float4* __restrict__ Q = sorted + (size_t)g * N;
    const unsigned* __restrict__ L = wlist + (size_t)g * N;

    unsigned cnt = wcnt[g];
    unsigned nb = (cnt + 7u) >> 3;           // batches of 8
    double acc = 0.0;

    for (unsigned bi = (unsigned)(ci * 4 + wid); bi < nb; bi += 512u) {
        unsigned base = bi * 8u;
        int nv = min(8, (int)(cnt - base));
        float q2[8], ax[8], ay[8], az[8], tv[8];
#pragma unroll
        for (int u = 0; u < 8; ++u) {
            float4 q = make_float4(0.f, 0.f, 0.f, 0.f);
            if (u < nv) q = Q[L[base + u]];
            q2[u] = q.w;
            ax[u] = -2.f * q.x; ay[u] = -2.f * q.y; az[u] = -2.f * q.z;
            tv[u] = 1e30f;
        }
#pragma unroll 2
        for (int j = lane; j < N; j += 64) {
            float4 p = P[j];
#pragma unroll
            for (int u = 0; u < 8; ++u) {
                float t = fmaf(ax[u], p.x,
                          fmaf(ay[u], p.y, fmaf(az[u], p.z, p.w)));
                tv[u] = fminf(tv[u], t);
            }
        }
#pragma unroll
        for (int u = 0; u < 8; ++u) {
#pragma unroll
            for (int o = 32; o; o >>= 1)
                tv[u] = fminf(tv[u], __shfl_xor(tv[u], o, 64));
        }
        if (lane == 0) {
#pragma unroll
            for (int u = 0; u < 8; ++u)
                if (u < nv) acc += (double)fmaxf(0.f, q2[u] + tv[u]);
        }
    }

    __shared__ double sd[4];
    if (lane == 0) sd[wid] = acc;
    __syncthreads();
    if (threadIdx.x == 0)
        partialB[blockIdx.x] = sd[0] + sd[1] + sd[2] + sd[3];
}

// ---------------- k6: final reduction ----------------
__global__ __launch_bounds__(256) void k6_final(
    const double* __restrict__ pA, int nA, const double* __restrict__ pB,
    int nB, float* __restrict__ out)
{
    double s = 0.0;
    for (int i = threadIdx.x; i < nA; i += 256) s += pA[i];
    for (int i = threadIdx.x; i < nB; i += 256) s += pB[i];
#pragma unroll
    for (int o = 32; o; o >>= 1) s += __shfl_down(s, o, 64);
    __shared__ double sd[4];
    int wid = threadIdx.x >> 6, lane = threadIdx.x & 63;
    if (lane == 0) sd[wid] = s;
    __syncthreads();
    if (threadIdx.x == 0)
        out[0] = (float)((sd[0] + sd[1] + sd[2] + sd[3]) / (double)BATCH);
}

extern "C" void kernel_launch(void* const* d_in, const int* in_sizes, int n_in,
                              void* d_out, int out_size, void* d_ws, size_t ws_size,
                              hipStream_t stream)
{
    const float* ytrue = (const float*)d_in[0];
    const float* ypred = (const float*)d_in[1];
    int N = in_sizes[0] / (BATCH * 3);          // 8192
    size_t total = (size_t)NG * N;              // 131072
    int blkA = (int)(total / 16);               // 8192

    char* ws = (char*)d_ws;
    float4*   sorted  = (float4*)ws;   ws += total * sizeof(float4);     // 2 MB
    unsigned* cnt     = (unsigned*)ws; ws += (size_t)NG * NCELL * 4;     // 2 MB (fill)
    unsigned* sc      = (unsigned*)ws; ws += (size_t)NG * NCELL * 4;     // 2 MB
    unsigned* wlist   = (unsigned*)ws; ws += total * 4;                  // 512 KB
    double*   partialA = (double*)ws;  ws += (size_t)blkA * 8;           // 64 KB
    double*   partialB = (double*)ws;  ws += (size_t)K5B_BLK * 8;        // 16 KB
    float*    bbox    = (float*)ws;    ws += NG * 6 * sizeof(float);
    unsigned* wcnt    = (unsigned*)ws; ws += NG * 4;

    k1_bbox_zero<<<NG + 512, 256, 0, stream>>>(ytrue, ypred, N, bbox,
                                               (uint4*)cnt, wcnt);
    int ptB = (int)(total / 4 / 256);           // 128 blocks
    k2_hist<<<ptB, 256, 0, stream>>>(ytrue, ypred, N, bbox, cnt);
    k3_scan<<<NG, 1024, 0, stream>>>(cnt, sc);
    k4_scatter<<<ptB, 256, 0, stream>>>(ytrue, ypred, N, bbox, sc, cnt, sorted);
    k5a<<<blkA, 256, 0, stream>>>(sorted, sc, bbox, N, partialA, wlist, wcnt);
    k5b<<<K5B_BLK, 256, 0, stream>>>(sorted, wlist, wcnt, N, partialB);
    k6_final<<<1, 256, 0, stream>>>(partialA, blkA, partialB, K5B_BLK,
                                    (float*)d_out);
}